// Round 10
// baseline (108.629 us; speedup 1.0000x reference)
//
#include <hip/hip_runtime.h>

typedef _Float16 v8h __attribute__((ext_vector_type(8)));
typedef float v16f __attribute__((ext_vector_type(16)));

#define BB 8
#define NN 8192
#define MM 8192
#define NCHUNK 8             // M staged in 8 chunks of 1024
#define JTC 32               // j-tiles (32 pts) per chunk
#define CPTS (JTC * 32)      // 1024 points per chunk
#define TPB 128              // 2 waves per block
#define PPT (CPTS / TPB)     // 8 points staged per thread per chunk

// Homogeneous K=16 encoding (k = (lane>>5)*8 + reg):
//  k=0..2 : A = yhat_c          B = -2*xhat_c
//  k=3,4  : A = (y2)_hi,(y2)_lo B = 1, 1
//  k=5,6  : A = 1, 1            B = (x2)_hi,(x2)_lo
//  k>=7   : 0
// => D[j][i] = |xhat_i - yhat_j|^2 exactly in fp32 accum (no cancellation loss).

__device__ __forceinline__ v8h cvt_a(float x, float y, float z) {
    _Float16 h0 = (_Float16)x, h1 = (_Float16)y, h2 = (_Float16)z;
    float y0 = (float)h0, y1 = (float)h1, y2v = (float)h2;
    float s = fmaf(y0, y0, fmaf(y1, y1, y2v * y2v));
    _Float16 shi = (_Float16)s;
    _Float16 slo = (_Float16)(s - (float)shi);
    v8h v = {h0, h1, h2, shi, slo, (_Float16)1.0f, (_Float16)1.0f, (_Float16)0.0f};
    return v;
}

__global__ __launch_bounds__(TPB, 1) void chamfer_mega(const float* __restrict__ xyz1,
                                                       const float* __restrict__ xyz2,
                                                       float* __restrict__ out) {
    __shared__ v8h aLds[2][JTC * 64];  // 64 KB double-buffered A-frag chunks
    __shared__ float ls[2];

    int ig = blockIdx.x & 63;   // 64 i-groups of 128 points
    int b  = blockIdx.x >> 6;   // 8 batches -> grid 512 = 2 blocks/CU
    int t  = threadIdx.x;
    int wid = t >> 6;
    int lane = t & 63;
    int laneq = lane & 31;
    int half = lane >> 5;

    // ---- zero khalf=1 slots of BOTH buffers once (k=8..15 contribute 0) ----
    {
        v8h z = {};
#pragma unroll
        for (int r = 0; r < 16; ++r) {
            int s = r * TPB + t;            // 0..2047
            int buf = s >> 10;
            int jt  = (s >> 5) & 31;
            int sl  = s & 31;
            aLds[buf][jt * 64 + 32 + sl] = z;
        }
    }

    // ---- inline B-frag pack: this wave's two i-tiles (one-time) ----
    int it0 = (ig * 2 + wid) * 2;
    v8h bf0, bf1;
#pragma unroll
    for (int tt = 0; tt < 2; ++tt) {
        int i = (it0 + tt) * 32 + laneq;
        const float* p = xyz1 + ((size_t)b * NN + i) * 3;
        _Float16 h0 = (_Float16)p[0], h1 = (_Float16)p[1], h2 = (_Float16)p[2];
        float x0 = (float)h0, x1 = (float)h1, x2v = (float)h2;
        float s = fmaf(x0, x0, fmaf(x1, x1, x2v * x2v));
        _Float16 shi = (_Float16)s;
        _Float16 slo = (_Float16)(s - (float)shi);
        v8h v = {};
        if (half == 0) {
            v[0] = (_Float16)(-2.0f * x0);
            v[1] = (_Float16)(-2.0f * x1);
            v[2] = (_Float16)(-2.0f * x2v);
            v[3] = (_Float16)1.0f; v[4] = (_Float16)1.0f;
            v[5] = shi; v[6] = slo;
        }
        if (tt == 0) bf0 = v; else bf1 = v;
    }

    // ---- stage chunk 0 into buf 0 (8 points/thread: 6 float4 raw -> cvt -> ds_write) ----
    const float* xb = xyz2 + (size_t)b * MM * 3;
    float4 pr[6];
    {
        const float4* src = (const float4*)(xb + (size_t)t * PPT * 3);
#pragma unroll
        for (int r = 0; r < 6; ++r) pr[r] = src[r];
        const float* fl = (const float*)pr;
#pragma unroll
        for (int k = 0; k < PPT; ++k) {
            int p = t * PPT + k;
            aLds[0][(p >> 5) * 64 + (p & 31)] = cvt_a(fl[3 * k], fl[3 * k + 1], fl[3 * k + 2]);
        }
    }
    __syncthreads();

    // ---- main loop over 8 chunks, double-buffered ----
    const v16f zc = {};
    float m0 = 1e30f, m1 = 1e30f;
#pragma unroll 1
    for (int c = 0; c < NCHUNK; ++c) {
        int cb = c & 1;
        if (c + 1 < NCHUNK) {  // prefetch next chunk's raw floats (latency hidden by compute)
            const float4* src = (const float4*)(xb + ((size_t)(c + 1) * CPTS + (size_t)t * PPT) * 3);
#pragma unroll
            for (int r = 0; r < 6; ++r) pr[r] = src[r];
        }
#pragma unroll 4
        for (int jt = 0; jt < JTC; ++jt) {
            v8h a = aLds[cb][jt * 64 + lane];
            v16f c0 = __builtin_amdgcn_mfma_f32_32x32x16_f16(a, bf0, zc, 0, 0, 0);
            v16f c1 = __builtin_amdgcn_mfma_f32_32x32x16_f16(a, bf1, zc, 0, 0, 0);
#pragma unroll
            for (int r = 0; r < 16; r += 4) {
                m0 = fminf(m0, fminf(fminf(c0[r], c0[r + 1]), fminf(c0[r + 2], c0[r + 3])));
                m1 = fminf(m1, fminf(fminf(c1[r], c1[r + 1]), fminf(c1[r + 2], c1[r + 3])));
            }
        }
        if (c + 1 < NCHUNK) {  // convert + write into the other buffer
            const float* fl = (const float*)pr;
#pragma unroll
            for (int k = 0; k < PPT; ++k) {
                int p = t * PPT + k;
                aLds[cb ^ 1][(p >> 5) * 64 + (p & 31)] = cvt_a(fl[3 * k], fl[3 * k + 1], fl[3 * k + 2]);
            }
        }
        __syncthreads();
    }

    // ---- epilogue: combine row-halves, per-lane final min, block sum, one atomic ----
    m0 = fminf(m0, __shfl_xor(m0, 32));
    m1 = fminf(m1, __shfl_xor(m1, 32));
    float mv = half ? m1 : m0;  // every lane owns one distinct i

    float s = mv;
#pragma unroll
    for (int off = 32; off > 0; off >>= 1) s += __shfl_down(s, off);
    if (lane == 0) ls[wid] = s;
    __syncthreads();
    if (t == 0) atomicAdd(out, (ls[0] + ls[1]) * (1.0f / (float)(BB * NN)));
}

extern "C" void kernel_launch(void* const* d_in, const int* in_sizes, int n_in,
                              void* d_out, int out_size, void* d_ws, size_t ws_size,
                              hipStream_t stream) {
    const float* xyz1 = (const float*)d_in[0];
    const float* xyz2 = (const float*)d_in[1];
    float* out = (float*)d_out;

    hipMemsetAsync(out, 0, sizeof(float), stream);
    chamfer_mega<<<BB * 64, TPB, 0, stream>>>(xyz1, xyz2, out);
}

// Round 11
// 76.263 us; speedup vs baseline: 1.4244x; 1.4244x over previous
//
#include <hip/hip_runtime.h>

typedef _Float16 v8h __attribute__((ext_vector_type(8)));
typedef float v16f __attribute__((ext_vector_type(16)));

#define BB 8
#define NN 8192
#define MM 8192
#define SPLITM 8          // j-chunks per batch
#define CPTS 1024         // xyz2 points per chunk
#define JTC 32            // 32-point j-tiles per chunk
#define TPB 256           // 4 waves

// Homogeneous K=16 encoding (k = (lane>>5)*8 + reg):
//  k=0..2 : A = yhat_c          B = -2*xhat_c
//  k=3,4  : A = (y2)_hi,(y2)_lo B = 1, 1
//  k=5,6  : A = 1, 1            B = (x2)_hi,(x2)_lo
//  k=7..15: B = 0  =>  A's k>=8 slots are DON'T-CARE (finite) -> A stored compressed,
//  all lanes read the khalf=0 frag (lane-pair broadcast, conflict-free).

__device__ __forceinline__ float min3f(float a, float b, float c) {
    return fminf(fminf(a, b), c);  // -> v_min3_f32
}

__global__ __launch_bounds__(TPB, 4) void chamfer_min_mfma(const float* __restrict__ xyz1,
                                                           const float* __restrict__ xyz2,
                                                           float* __restrict__ pmins) {
    __shared__ v8h aLds[CPTS];  // 16 KB compressed A-frags

    // grid = 2048: bid = b*256 + jchunk*32 + ig
    int ig     = blockIdx.x & 31;
    int jchunk = (blockIdx.x >> 5) & 7;
    int b      = blockIdx.x >> 8;
    int t = threadIdx.x;
    int wid = t >> 6;
    int lane = t & 63;
    int laneq = lane & 31;
    int half = lane >> 5;

    // ---- fused A pack: convert this chunk's 1024 xyz2 points, 4/thread ----
    // p = k*256+t => ds_write_b128 at 16B/lane contiguous: conflict-free
    const float* srcA = xyz2 + ((size_t)b * MM + (size_t)jchunk * CPTS) * 3;
#pragma unroll
    for (int k = 0; k < CPTS / TPB; ++k) {
        int p = k * TPB + t;
        float x = srcA[p * 3 + 0], y = srcA[p * 3 + 1], z = srcA[p * 3 + 2];
        _Float16 h0 = (_Float16)x, h1 = (_Float16)y, h2 = (_Float16)z;
        float y0 = (float)h0, y1 = (float)h1, y2v = (float)h2;
        float s = fmaf(y0, y0, fmaf(y1, y1, y2v * y2v));
        _Float16 shi = (_Float16)s;
        _Float16 slo = (_Float16)(s - (float)shi);
        v8h v = {h0, h1, h2, shi, slo, (_Float16)1.0f, (_Float16)1.0f, (_Float16)0.0f};
        aLds[p] = v;
    }

    // ---- fused B pack: this wave's two i-tiles (khalf=1 lanes stay zero!) ----
    int it0 = (ig * 4 + wid) * 2;
    v8h bf0 = {}, bf1 = {};
#pragma unroll
    for (int tt = 0; tt < 2; ++tt) {
        int i = (it0 + tt) * 32 + laneq;
        const float* p = xyz1 + ((size_t)b * NN + i) * 3;
        _Float16 h0 = (_Float16)p[0], h1 = (_Float16)p[1], h2 = (_Float16)p[2];
        float x0 = (float)h0, x1 = (float)h1, x2v = (float)h2;
        float s = fmaf(x0, x0, fmaf(x1, x1, x2v * x2v));
        _Float16 shi = (_Float16)s;
        _Float16 slo = (_Float16)(s - (float)shi);
        v8h v = {};
        if (half == 0) {
            v[0] = (_Float16)(-2.0f * x0);
            v[1] = (_Float16)(-2.0f * x1);
            v[2] = (_Float16)(-2.0f * x2v);
            v[3] = (_Float16)1.0f; v[4] = (_Float16)1.0f;
            v[5] = shi; v[6] = slo;
        }
        if (tt == 0) bf0 = v; else bf1 = v;
    }

    __syncthreads();

    // ---- main loop: 1 broadcast ds_read + 2 MFMA + 16 v_min3 per j-tile ----
    const v16f zc = {};
    float m0g[4] = {1e30f, 1e30f, 1e30f, 1e30f};
    float m1g[4] = {1e30f, 1e30f, 1e30f, 1e30f};
#pragma unroll 2
    for (int jt = 0; jt < JTC; ++jt) {
        v8h a = aLds[jt * 32 + laneq];  // lanes l and l+32: same addr (free broadcast)
        v16f c0 = __builtin_amdgcn_mfma_f32_32x32x16_f16(a, bf0, zc, 0, 0, 0);
        v16f c1 = __builtin_amdgcn_mfma_f32_32x32x16_f16(a, bf1, zc, 0, 0, 0);
#pragma unroll
        for (int g = 0; g < 4; ++g) {
            int r = 4 * g;
            m0g[g] = min3f(min3f(c0[r], c0[r + 1], c0[r + 2]), c0[r + 3], m0g[g]);
            m1g[g] = min3f(min3f(c1[r], c1[r + 1], c1[r + 2]), c1[r + 3], m1g[g]);
        }
    }

    // ---- epilogue: merge groups + row-halves; one dword per lane ----
    float m0 = fminf(min3f(m0g[0], m0g[1], m0g[2]), m0g[3]);
    float m1 = fminf(min3f(m1g[0], m1g[1], m1g[2]), m1g[3]);
    m0 = fminf(m0, __shfl_xor(m0, 32));
    m1 = fminf(m1, __shfl_xor(m1, 32));
    int i = (it0 + half) * 32 + laneq;
    pmins[(size_t)jchunk * (BB * NN) + (size_t)b * NN + i] = half ? m1 : m0;
}

__global__ __launch_bounds__(256) void chamfer_reduce(const float* __restrict__ pmins,
                                                      float* __restrict__ out) {
    int i = blockIdx.x * 256 + threadIdx.x;  // grid 256 blocks
    float m = pmins[i];
#pragma unroll
    for (int sp = 1; sp < SPLITM; ++sp)
        m = fminf(m, pmins[(size_t)sp * (BB * NN) + i]);
    float s = m;
#pragma unroll
    for (int off = 32; off > 0; off >>= 1) s += __shfl_down(s, off);
    __shared__ float ls[4];
    int lane = threadIdx.x & 63, wv = threadIdx.x >> 6;
    if (lane == 0) ls[wv] = s;
    __syncthreads();
    if (threadIdx.x == 0) {
        float tt = (ls[0] + ls[1]) + (ls[2] + ls[3]);
        atomicAdd(out, tt * (1.0f / (float)(BB * NN)));
    }
}

extern "C" void kernel_launch(void* const* d_in, const int* in_sizes, int n_in,
                              void* d_out, int out_size, void* d_ws, size_t ws_size,
                              hipStream_t stream) {
    const float* xyz1 = (const float*)d_in[0];
    const float* xyz2 = (const float*)d_in[1];
    float* out = (float*)d_out;
    float* pmins = (float*)d_ws;

    hipMemsetAsync(out, 0, sizeof(float), stream);
    chamfer_min_mfma<<<BB * SPLITM * 32, TPB, 0, stream>>>(xyz1, xyz2, pmins);
    chamfer_reduce<<<(BB * NN) / 256, 256, 0, stream>>>(pmins, out);
}